// Round 9
// baseline (437.365 us; speedup 1.0000x reference)
//
#include <hip/hip_runtime.h>
#include <hip/hip_bf16.h>

#define Bq 4
#define Cc 128
#define Ff 64
#define Tt 2048
#define CF 8192     // C*F
#define NCHUNK 32   // cf chunks for QK pass
#define CHUNK 256   // cf per chunk

typedef __attribute__((ext_vector_type(4))) float f32x4;
typedef __attribute__((ext_vector_type(8))) short bf16x8;

__device__ inline ushort f2bf(float f) {
    __hip_bfloat16 h = __float2bfloat16(f);   // round-to-nearest
    return *reinterpret_cast<ushort*>(&h);
}

__device__ inline void gload_lds16(const void* g, void* l) {
    __builtin_amdgcn_global_load_lds(
        (const __attribute__((address_space(1))) void*)g,
        (__attribute__((address_space(3))) void*)l, 16, 0, 0);
}

// ---------------------------------------------------------------------------
// K1: merged prep.
// ---------------------------------------------------------------------------
__global__ void k_prep(const float* __restrict__ Wq_lin, const float* __restrict__ Wq_conv,
                       const float* __restrict__ Wk_lin, const float* __restrict__ Wk_conv,
                       const float* __restrict__ bq_conv, const float* __restrict__ bq_lin,
                       const float* __restrict__ bk_conv, const float* __restrict__ bk_lin,
                       const float* __restrict__ Wv,
                       float* __restrict__ weff, float* __restrict__ cqk,
                       ushort* __restrict__ Wvb) {
    int blk = blockIdx.x;
    if (blk < 640) {
        int gid = blk * 256 + threadIdx.x;
        if (gid >= CF * 20) return;
        int cf = gid / 20, d = gid % 20;
        int c = cf >> 6, f = cf & 63;
        float s = 0.f;
        if (d < 10) {
            #pragma unroll
            for (int o = 0; o < 4; ++o) s += Wq_lin[d * 256 + o * 64 + f] * Wq_conv[o * 128 + c];
        } else {
            int dd = d - 10;
            #pragma unroll
            for (int o = 0; o < 4; ++o) s += Wk_lin[dd * 256 + o * 64 + f] * Wk_conv[o * 128 + c];
        }
        weff[cf * 20 + d] = s;
    } else if (blk < 704) {
        int i = (blk - 640) * 256 + threadIdx.x;
        if (i < 16384) Wvb[i] = f2bf(Wv[i]);
    } else {
        int d = threadIdx.x;
        if (d >= 20) return;
        float s;
        if (d < 10) {
            s = bq_lin[d];
            for (int o = 0; o < 4; ++o) {
                float bb = bq_conv[o];
                for (int f = 0; f < 64; ++f) s += Wq_lin[d * 256 + o * 64 + f] * bb;
            }
        } else {
            int dd = d - 10;
            s = bk_lin[dd];
            for (int o = 0; o < 4; ++o) {
                float bb = bk_conv[o];
                for (int f = 0; f < 64; ++f) s += Wk_lin[dd * 256 + o * 64 + f] * bb;
            }
        }
        cqk[d] = s;
    }
}

// ---------------------------------------------------------------------------
// K2: QK partials + x->bf16 side-write.
// ---------------------------------------------------------------------------
__global__ __launch_bounds__(256) void k_qk(const float* __restrict__ x,
                                            const float* __restrict__ weff,
                                            float* __restrict__ partial,
                                            ushort* __restrict__ xbf) {
    int blk = blockIdx.x;
    int tt = blk & 3;
    int ch = (blk >> 2) & 31;
    int b  = blk >> 7;
    int t = tt * 512 + threadIdx.x * 2;
    const float* xb = x + (size_t)b * CF * Tt;
    ushort* xob = xbf + (size_t)b * CF * Tt;
    float acc[20][2];
    #pragma unroll
    for (int d = 0; d < 20; ++d) { acc[d][0] = 0.f; acc[d][1] = 0.f; }
    int cf0 = ch * CHUNK;
    for (int cf = cf0; cf < cf0 + CHUNK; ++cf) {
        float2 xv = *(const float2*)(xb + (size_t)cf * Tt + t);
        *(ushort2*)(xob + (size_t)cf * Tt + t) = make_ushort2(f2bf(xv.x), f2bf(xv.y));
        const float* w = weff + cf * 20;   // uniform address -> s_loads
        #pragma unroll
        for (int d = 0; d < 20; ++d) {
            float wv = w[d];
            acc[d][0] += wv * xv.x;
            acc[d][1] += wv * xv.y;
        }
    }
    float* pb = partial + (size_t)(b * NCHUNK + ch) * 20 * Tt;
    #pragma unroll
    for (int d = 0; d < 20; ++d)
        *(float2*)(pb + (size_t)d * Tt + t) = make_float2(acc[d][0], acc[d][1]);
}

// K3: reduce partials + const -> Q[b][t][10], Kt[b][10][t].  grid (32,20) x 256
__global__ void k_qkred(const float* __restrict__ partial, const float* __restrict__ cqk,
                        float* __restrict__ Q, float* __restrict__ Kt) {
    int t = blockIdx.x * 256 + threadIdx.x;  // 0..8191
    int d = blockIdx.y;                      // 0..19
    int b = t >> 11, tl = t & 2047;
    float s = cqk[d];
    #pragma unroll 4
    for (int ch = 0; ch < NCHUNK; ++ch)
        s += partial[((size_t)(b * NCHUNK + ch) * 20 + d) * Tt + tl];
    if (d < 10) Q[(size_t)(b * 2048 + tl) * 10 + d] = s;
    else        Kt[((size_t)b * 10 + (d - 10)) * Tt + tl] = s;
}

// ---------------------------------------------------------------------------
// K4: energy + softmax -> A_bf16[b][i][j].
// ---------------------------------------------------------------------------
__global__ __launch_bounds__(256) void k_att(const float* __restrict__ Q,
                                             const float* __restrict__ Kt,
                                             ushort* __restrict__ A) {
    int bi = blockIdx.x;
    int b = bi >> 11;
    __shared__ float qs[10];
    __shared__ float wmax[4];
    __shared__ float wsum[4];
    int tid = threadIdx.x;
    int lane = tid & 63, wid = tid >> 6;
    if (tid < 10) qs[tid] = Q[(size_t)bi * 10 + tid];
    __syncthreads();
    float q[10];
    #pragma unroll
    for (int d = 0; d < 10; ++d) q[d] = qs[d];
    const float* kb = Kt + (size_t)b * 10 * Tt;
    float e[8];
    #pragma unroll
    for (int jj = 0; jj < 8; ++jj) {
        int j = jj * 256 + tid;
        float s = 0.f;
        #pragma unroll
        for (int d = 0; d < 10; ++d) s += q[d] * kb[(size_t)d * Tt + j];
        e[jj] = s;
    }
    float m = e[0];
    #pragma unroll
    for (int jj = 1; jj < 8; ++jj) m = fmaxf(m, e[jj]);
    #pragma unroll
    for (int off = 32; off > 0; off >>= 1) m = fmaxf(m, __shfl_xor(m, off));
    if (lane == 0) wmax[wid] = m;
    __syncthreads();
    float M = fmaxf(fmaxf(wmax[0], wmax[1]), fmaxf(wmax[2], wmax[3]));
    float sum = 0.f;
    #pragma unroll
    for (int jj = 0; jj < 8; ++jj) { e[jj] = __expf(e[jj] - M); sum += e[jj]; }
    #pragma unroll
    for (int off = 32; off > 0; off >>= 1) sum += __shfl_xor(sum, off);
    if (lane == 0) wsum[wid] = sum;
    __syncthreads();
    float inv = 1.f / (wsum[0] + wsum[1] + wsum[2] + wsum[3]);
    ushort* arow = A + (size_t)bi * Tt;
    #pragma unroll
    for (int jj = 0; jj < 8; ++jj) arow[jj * 256 + tid] = f2bf(e[jj] * inv);
}

// ---------------------------------------------------------------------------
// K5: fused PV + channel conv — 256x256 counted-vmcnt schedule with m201
// per-phase cadence: each 16-MFMA quadrant wrapped in
//   {reads; stages; s_barrier; lgkmcnt(0); setprio; MFMA; setprio; s_barrier}
// so each phase's ds_read burst overlaps the PREVIOUS phase's matrix-pipe
// drain (s_barrier does not flush the MFMA pipe). Staging order, vmcnt
// placement, quadrant order == round-8 (proven); output bit-identical.
// grid (32 f-pairs, 8 i-tiles, 4 b) x 512
// ---------------------------------------------------------------------------
__global__ __launch_bounds__(512, 2) void k_pv_conv(const ushort* __restrict__ Xb,
                                                    const ushort* __restrict__ Ab,
                                                    const ushort* __restrict__ Wvb,
                                                    const float* __restrict__ bv,
                                                    float* __restrict__ out) {
    __shared__ float smemf[32768];           // 128 KB
    char* smem = (char*)smemf;
    int fb = blockIdx.x, ib = blockIdx.y, b = blockIdx.z;
    int f0 = fb * 2;
    int tid = threadIdx.x;
    int w = tid >> 6, l = tid & 63;
    int wm = w >> 2, wn = w & 3;             // stage-1 wave grid 2(M) x 4(N)
    int frow = l & 15, q = l >> 4, f7 = frow & 7;

    const ushort* xb0 = Xb + (size_t)b * CF * Tt + (size_t)f0 * Tt;
    const ushort* ab0 = Ab + (size_t)b * Tt * Tt + (size_t)ib * 256 * Tt;

    // staging source coords (pre-swizzled): row = g*64 + w*8 + (l>>3)
    int row_l = w * 8 + (l >> 3);
    int col_s = (((l & 7) ^ (l >> 3)) << 3);
    const ushort* srcB[4]; const ushort* srcA[4];
    #pragma unroll
    for (int g = 0; g < 4; ++g) {
        int row = g * 64 + row_l;
        srcB[g] = ab0 + (size_t)row * Tt + col_s;
        int n = (row & 127) * 64 + (row >> 7);   // n = c'*64 + (f - f0)
        srcA[g] = xb0 + (size_t)n * Tt + col_s;
    }

#define STG_B(g) gload_lds16(srcB[g] + k1, nb + (g) * 8192 + w * 1024)
#define STG_A(g) gload_lds16(srcA[g] + k1, nb + 32768 + (g) * 8192 + w * 1024)

    // fragment-read constants
    int swzk0 = (q ^ f7) << 4;
    int swzk1 = ((4 + q) ^ f7) << 4;
    int aBase = 32768 + (wm * 128 + frow) * 128;
    int bBase = (wn * 64 + frow) * 128;

#define READ_A(cb, MH)                                                          \
    _Pragma("unroll")                                                           \
    for (int mm = 0; mm < 4; ++mm) {                                            \
        afr[mm][0] = *(const bf16x8*)((cb) + aBase + (MH) * 8192 + mm * 2048 + swzk0); \
        afr[mm][1] = *(const bf16x8*)((cb) + aBase + (MH) * 8192 + mm * 2048 + swzk1); \
    }
#define READ_B(cb, NH, DST)                                                     \
    _Pragma("unroll")                                                           \
    for (int nn = 0; nn < 2; ++nn) {                                            \
        DST[nn][0] = *(const bf16x8*)((cb) + bBase + (NH) * 4096 + nn * 2048 + swzk0); \
        DST[nn][1] = *(const bf16x8*)((cb) + bBase + (NH) * 4096 + nn * 2048 + swzk1); \
    }
#define MFMA_Q(MH, NH, BFR)                                                     \
    __builtin_amdgcn_s_setprio(1);                                              \
    _Pragma("unroll")                                                           \
    for (int kk = 0; kk < 2; ++kk)                                              \
        _Pragma("unroll")                                                       \
        for (int mm = 0; mm < 4; ++mm)                                          \
            _Pragma("unroll")                                                   \
            for (int nn = 0; nn < 2; ++nn)                                      \
                acc[(MH) * 4 + mm][(NH) * 2 + nn] =                             \
                    __builtin_amdgcn_mfma_f32_16x16x32_bf16(                    \
                        afr[mm][kk], BFR[nn][kk],                               \
                        acc[(MH) * 4 + mm][(NH) * 2 + nn], 0, 0, 0);            \
    __builtin_amdgcn_s_setprio(0);

#define BARX() __builtin_amdgcn_s_barrier()
#define LGKM0() asm volatile("s_waitcnt lgkmcnt(0)" ::: "memory")

// One K=64 iteration, m201 cadence.  CBUF = read buffer, NBUF = stage buffer.
#define ITER_BODY(CBUF, NBUF, T, ST) do {                                \
        const char* cb = (CBUF);                                         \
        char* nb = (NBUF);                                               \
        int k1 = ((T) + 1) * 64;                                         \
        if (!(ST)) asm volatile("s_waitcnt vmcnt(0)" ::: "memory");      \
        bf16x8 afr[4][2], bfr0[2][2], bfr1[2][2];                        \
        /* P1: quadrant (0,0) */                                         \
        READ_A(cb, 0)                                                    \
        READ_B(cb, 0, bfr0)                                              \
        if (ST) { STG_B(0); STG_B(1); }                                  \
        BARX(); LGKM0();                                                 \
        MFMA_Q(0, 0, bfr0)                                               \
        BARX();                                                          \
        /* P2: quadrant (0,1) */                                         \
        READ_B(cb, 1, bfr1)                                              \
        if (ST) { STG_B(2); STG_B(3); }                                  \
        BARX(); LGKM0();                                                 \
        MFMA_Q(0, 1, bfr1)                                               \
        asm volatile("s_waitcnt vmcnt(4)" ::: "memory");                 \
        BARX();   /* A1,A3 of cb now globally visible */                 \
        /* P3: quadrant (1,1) */                                         \
        READ_A(cb, 1)                                                    \
        if (ST) { STG_A(0); STG_A(2); }                                  \
        BARX(); LGKM0();                                                 \
        MFMA_Q(1, 1, bfr1)                                               \
        BARX();                                                          \
        /* P4: quadrant (1,0) — operands already in regs */              \
        if (ST) { STG_A(1); STG_A(3); }                                  \
        MFMA_Q(1, 0, bfr0)                                               \
        asm volatile("s_waitcnt vmcnt(2)" ::: "memory");                 \
        BARX();   /* B0..B3,A0,A2 of nb now globally visible */          \
    } while (0)

    f32x4 acc[8][4];
    #pragma unroll
    for (int m = 0; m < 8; ++m)
        #pragma unroll
        for (int n = 0; n < 4; ++n) acc[m][n] = (f32x4){0.f, 0.f, 0.f, 0.f};

    // prologue: stage buf0, queue order = steady state [B0..B3, A0,A2,A1,A3]
    {
        char* nb = smem;
        int k1 = 0;
        STG_B(0); STG_B(1); STG_B(2); STG_B(3);
        STG_A(0); STG_A(2); STG_A(1); STG_A(3);
    }
    asm volatile("s_waitcnt vmcnt(2)" ::: "memory");
    __builtin_amdgcn_s_barrier();   // -> B0..B3, A0, A2 of ALL waves visible

    #pragma unroll 1
    for (int tp = 0; tp < 15; ++tp) {
        ITER_BODY(smem,         smem + 65536, 2 * tp,     true);
        ITER_BODY(smem + 65536, smem,         2 * tp + 1, true);
    }
    ITER_BODY(smem,         smem + 65536, 30, true);
    ITER_BODY(smem + 65536, smem,         31, false);
    __syncthreads();   // all MFMAs/reads done before Yt overlays smem

    // ---- transpose acc -> Yt[f=wm][i][c'] (bf16, swizzled), full-LDS overlay ----
    // acc[m][n][r] = Y[c'_loc = m*16 + q*4 + r][i = wn*64 + n*16 + frow]
    {
        char* Yt = smem + wm * 65536;
        #pragma unroll
        for (int n = 0; n < 4; ++n) {
            int i = wn * 64 + n * 16 + frow;
            int swz = (i & 7) << 4;
            #pragma unroll
            for (int m = 0; m < 8; ++m) {
                int cp = m * 16 + q * 4;
                ushort4 v;
                v.x = f2bf(acc[m][n][0]); v.y = f2bf(acc[m][n][1]);
                v.z = f2bf(acc[m][n][2]); v.w = f2bf(acc[m][n][3]);
                *(ushort4*)(Yt + ((i * 256 + cp * 2) ^ swz)) = v;
            }
        }
    }
    __syncthreads();

    // ---- stage 2: Out_f[c][i] = sum_c' Wvb[c][c'] * Yt[f][i][c'], K=128 ----
    int fh = w >> 2, wn2 = w & 3;
    const char* ytb = smem + fh * 65536;
    f32x4 acc2[8][4];
    #pragma unroll
    for (int m = 0; m < 8; ++m)
        #pragma unroll
        for (int n = 0; n < 4; ++n) acc2[m][n] = (f32x4){0.f, 0.f, 0.f, 0.f};
    #pragma unroll
    for (int ks = 0; ks < 4; ++ks) {
        int kofs = ks * 32 + q * 8;
        bf16x8 a2[8], b2[4];
        #pragma unroll
        for (int m = 0; m < 8; ++m)
            a2[m] = *(const bf16x8*)&Wvb[(m * 16 + frow) * 128 + kofs];
        #pragma unroll
        for (int n = 0; n < 4; ++n) {
            int i = wn2 * 64 + n * 16 + frow;
            b2[n] = *(const bf16x8*)(ytb + ((i * 256 + kofs * 2) ^ ((i & 7) << 4)));
        }
        #pragma unroll
        for (int m = 0; m < 8; ++m)
            #pragma unroll
            for (int n = 0; n < 4; ++n)
                acc2[m][n] = __builtin_amdgcn_mfma_f32_16x16x32_bf16(a2[m], b2[n], acc2[m][n], 0, 0, 0);
    }

    // ---- bias + write d_out ----
    float* ob = out + (size_t)b * CF * Tt + (size_t)(f0 + fh) * Tt
                    + (size_t)ib * 256 + wn2 * 64;
    #pragma unroll
    for (int m = 0; m < 8; ++m) {
        #pragma unroll
        for (int r = 0; r < 4; ++r) {
            int c = m * 16 + q * 4 + r;
            float bvv = bv[c];
            #pragma unroll
            for (int n = 0; n < 4; ++n)
                ob[(size_t)c * 64 * Tt + n * 16 + frow] = acc2[m][n][r] + bvv;
        }
    }
#undef STG_A
#undef STG_B
#undef READ_A
#undef READ_B
#undef MFMA_Q
#undef ITER_BODY
#undef BARX
#undef LGKM0
}

// ---------------------------------------------------------------------------
extern "C" void kernel_launch(void* const* d_in, const int* in_sizes, int n_in,
                              void* d_out, int out_size, void* d_ws, size_t ws_size,
                              hipStream_t stream) {
    const float* x       = (const float*)d_in[0];
    const float* Wq_conv = (const float*)d_in[1];
    const float* bq_conv = (const float*)d_in[2];
    const float* Wq_lin  = (const float*)d_in[3];
    const float* bq_lin  = (const float*)d_in[4];
    const float* Wk_conv = (const float*)d_in[5];
    const float* bk_conv = (const float*)d_in[6];
    const float* Wk_lin  = (const float*)d_in[7];
    const float* bk_lin  = (const float*)d_in[8];
    const float* Wv      = (const float*)d_in[9];
    const float* bv      = (const float*)d_in[10];
    float* out = (float*)d_out;

    float* ws   = (float*)d_ws;
    float* weff = ws;                         // 163840
    float* cqk  = weff + 163840;              // 32
    float* part = cqk + 32;                   // 5242880
    float* Qb   = part + 5242880;             // 81920
    float* Ktb  = Qb + 81920;                 // 81920
    float* Abf_f = Ktb + 81920;               // 8388608 floats = 16.7M bf16
    float* Xbf_f = Abf_f + 8388608;           // 33554432 floats = 67.1M bf16
    float* Wvb_f = Xbf_f + 33554432;          // 8192 floats = 16384 bf16
    ushort* Abf = (ushort*)Abf_f;
    ushort* Xbf = (ushort*)Xbf_f;
    ushort* Wvb = (ushort*)Wvb_f;

    k_prep <<<705, 256, 0, stream>>>(Wq_lin, Wq_conv, Wk_lin, Wk_conv,
                                     bq_conv, bq_lin, bk_conv, bk_lin, Wv,
                                     weff, cqk, Wvb);
    k_qk   <<<512, 256, 0, stream>>>(x, weff, part, Xbf);
    k_qkred<<<dim3(32, 20), 256, 0, stream>>>(part, cqk, Qb, Ktb);
    k_att  <<<8192, 256, 0, stream>>>(Qb, Ktb, Abf);
    k_pv_conv<<<dim3(32, 8, 4), 512, 0, stream>>>(Xbf, Abf, Wvb, bv, out);
}